// Round 5
// baseline (108.382 us; speedup 1.0000x reference)
//
#include <hip/hip_runtime.h>

// InversePreEmphasis: h_t = tanh(x_t + 0.97*h_{t-1}) along T, per row.
// Chunked-parallel with warm-up (per-step contraction 0.97*(1-h^2), typ ~0.6).
// R5: S=64, W=32, 2048 blocks (32 waves/CU available). Schedule arranged so
// every s_waitcnt vmcnt(8) drains ONLY loads — stores are always the 8
// newest outstanding ops and are never waited on (R4 waited on stores).

constexpr int Bn = 256;
constexpr int T  = 131072;
constexpr int S  = 64;         // outputs per thread (2 groups)
constexpr int C  = T / S;      // 2048 chunks per row
constexpr int W  = 32;         // warm-up steps (1 group); residual ~1e-7 typ
constexpr int G  = 32;         // group = 128 bytes per thread

// tanh(x + 0.97h) = 1 - 2*rcp(exp2(g*x + 0.97*g*h) + 1),  g = 2*log2(e)
// state r: h = 1-2r;  t_k = fma(N2CG, r_{k-1}, gx_k);  gx_k = fma(GLN, x_k, CGLN)
constexpr float GLN  = 2.885390081777927f;          // 2*log2(e)
constexpr float CGLN = 0.97f * 2.885390081777927f;
constexpr float N2CG = -2.0f * 0.97f * 2.885390081777927f;

struct G8 { float4 v[8]; };

// Volatile asm load: compiler cannot sink or duplicate it.
#define LD4(dst, ptr, off) \
    asm volatile("global_load_dwordx4 %0, %1, off offset:" #off \
                 : "=&v"(dst) : "v"(ptr) : "memory")

// Counted wait + full scheduling fence (guide rule #18).
#define WAITV(n) do { \
    asm volatile("s_waitcnt vmcnt(" #n ")" ::: "memory"); \
    __builtin_amdgcn_sched_barrier(0); \
} while (0)

__device__ __forceinline__ void ldgrp(G8& g, const float* p) {
    LD4(g.v[0], p, 0);   LD4(g.v[1], p, 16);  LD4(g.v[2], p, 32);
    LD4(g.v[3], p, 48);  LD4(g.v[4], p, 64);  LD4(g.v[5], p, 80);
    LD4(g.v[6], p, 96);  LD4(g.v[7], p, 112);
}

template <bool OUT>
__device__ __forceinline__ void chainG(float& r, const G8& g, float* po) {
    float gx[G];
#pragma unroll
    for (int k = 0; k < 8; ++k) {             // off-chain pre-activations
        gx[4*k+0] = fmaf(GLN, g.v[k].x, CGLN);
        gx[4*k+1] = fmaf(GLN, g.v[k].y, CGLN);
        gx[4*k+2] = fmaf(GLN, g.v[k].z, CGLN);
        gx[4*k+3] = fmaf(GLN, g.v[k].w, CGLN);
    }
#pragma unroll
    for (int k = 0; k < 8; ++k) {
        float4 o; float t, e;
        t = fmaf(N2CG, r, gx[4*k+0]); e = __builtin_amdgcn_exp2f(t);
        r = __builtin_amdgcn_rcpf(e + 1.0f); o.x = fmaf(-2.0f, r, 1.0f);
        t = fmaf(N2CG, r, gx[4*k+1]); e = __builtin_amdgcn_exp2f(t);
        r = __builtin_amdgcn_rcpf(e + 1.0f); o.y = fmaf(-2.0f, r, 1.0f);
        t = fmaf(N2CG, r, gx[4*k+2]); e = __builtin_amdgcn_exp2f(t);
        r = __builtin_amdgcn_rcpf(e + 1.0f); o.z = fmaf(-2.0f, r, 1.0f);
        t = fmaf(N2CG, r, gx[4*k+3]); e = __builtin_amdgcn_exp2f(t);
        r = __builtin_amdgcn_rcpf(e + 1.0f); o.w = fmaf(-2.0f, r, 1.0f);
        if constexpr (OUT) *reinterpret_cast<float4*>(po + 4*k) = o;
    }
}

__global__ __launch_bounds__(256, 6) void ipe_scan_kernel(const float* __restrict__ x,
                                                          float* __restrict__ y) {
    const int tid = blockIdx.x * blockDim.x + threadIdx.x;
    const int b = tid / C;
    const int c = tid % C;
    const float* xr = x + (size_t)b * T;
    const int start = c * S;

    // c==0: dummy warm-up over x[0..W) (valid memory), state reset below.
    const float* pw = xr + (start >= W ? start - W : 0);
    const float* pb = xr + start;
    float*       po = y + (size_t)b * T + start;

    float r = 0.5f;         // h = 1 - 2r = 0

    G8 w, A, Bb;
    ldgrp(w, pw);           //  8 outstanding
    ldgrp(A, pb);           // 16

    WAITV(8);               // drains w only; A pending
    chainG<false>(r, w, nullptr);

    ldgrp(Bb, pb + G);      // A(8) + B(8) = 16
    WAITV(8);               // drains A only; B pending (no stores yet)

    if (c == 0) r = 0.5f;   // exact h0 = 0 for the first chunk

    chainG<true>(r, A, po);         // issues 8 stores -> [B(8), st(8)]
    WAITV(8);               // drains B only; stores are the 8 newest, not waited
    chainG<true>(r, Bb, po + G);    // final stores drain at s_endpgm
}

extern "C" void kernel_launch(void* const* d_in, const int* in_sizes, int n_in,
                              void* d_out, int out_size, void* d_ws, size_t ws_size,
                              hipStream_t stream) {
    const float* x = (const float*)d_in[0];
    float*       y = (float*)d_out;
    const int total_threads = Bn * C;          // 524288
    const int block = 256;
    const int grid = total_threads / block;    // 2048
    ipe_scan_kernel<<<grid, block, 0, stream>>>(x, y);
}

// Round 6
// 98.015 us; speedup vs baseline: 1.1058x; 1.1058x over previous
//
#include <hip/hip_runtime.h>

// InversePreEmphasis: h_t = tanh(x_t + 0.97*h_{t-1}) along T, per row.
// Chunked-parallel with warm-up (per-step contraction 0.97*(1-h^2)).
// R6: fix R4/R5 register spills. Only TWO G8 buffers live (w reused),
// no gx[] staging array (inline fmaf), launch_bounds(256,5) so the
// cap (~102 VGPR) exceeds demand (~80) -> no scratch traffic.
// Counted vmcnt waits: the 8 ops we wait for are always the oldest;
// stores are always newer than any waited-on load.

constexpr int Bn = 256;
constexpr int T  = 131072;
constexpr int S  = 64;         // outputs per thread (2 groups)
constexpr int C  = T / S;      // 2048 chunks per row
constexpr int W  = 32;         // warm-up steps (1 group)
constexpr int G  = 32;         // group = 128 bytes per thread

// tanh(x + 0.97h) = 1 - 2*rcp(exp2(g*x + 0.97*g*h) + 1),  g = 2*log2(e)
// state r: h = 1-2r;  t_k = fma(N2CG, r_{k-1}, gx_k);  gx_k = fma(GLN, x_k, CGLN)
constexpr float GLN  = 2.885390081777927f;          // 2*log2(e)
constexpr float CGLN = 0.97f * 2.885390081777927f;
constexpr float N2CG = -2.0f * 0.97f * 2.885390081777927f;

struct G8 { float4 v[8]; };

// Volatile asm load: compiler cannot sink or duplicate it.
#define LD4(dst, ptr, off) \
    asm volatile("global_load_dwordx4 %0, %1, off offset:" #off \
                 : "=&v"(dst) : "v"(ptr) : "memory")

// Counted wait + full scheduling fence (guide rule #18: consumers of the
// asm-load outputs must not be scheduled above the waitcnt).
#define WAITV(n) do { \
    asm volatile("s_waitcnt vmcnt(" #n ")" ::: "memory"); \
    __builtin_amdgcn_sched_barrier(0); \
} while (0)

__device__ __forceinline__ void ldgrp(G8& g, const float* p) {
    LD4(g.v[0], p, 0);   LD4(g.v[1], p, 16);  LD4(g.v[2], p, 32);
    LD4(g.v[3], p, 48);  LD4(g.v[4], p, 64);  LD4(g.v[5], p, 80);
    LD4(g.v[6], p, 96);  LD4(g.v[7], p, 112);
}

__device__ __forceinline__ float step1(float& r, float xin) {
    float t = fmaf(N2CG, r, fmaf(GLN, xin, CGLN));   // inner fmaf off-chain
    float e = __builtin_amdgcn_exp2f(t);
    r = __builtin_amdgcn_rcpf(e + 1.0f);
    return fmaf(-2.0f, r, 1.0f);
}

template <bool OUT>
__device__ __forceinline__ void chainG(float& r, const G8& g, float* po) {
#pragma unroll
    for (int k = 0; k < 8; ++k) {
        float4 o;
        o.x = step1(r, g.v[k].x);
        o.y = step1(r, g.v[k].y);
        o.z = step1(r, g.v[k].z);
        o.w = step1(r, g.v[k].w);
        if constexpr (OUT) *reinterpret_cast<float4*>(po + 4*k) = o;
    }
}

__global__ __launch_bounds__(256, 5) void ipe_scan_kernel(const float* __restrict__ x,
                                                          float* __restrict__ y) {
    const int tid = blockIdx.x * blockDim.x + threadIdx.x;
    const int b = tid / C;
    const int c = tid % C;
    const float* xr = x + (size_t)b * T;
    const int start = c * S;

    // c==0: dummy warm-up over x[0..W) (valid memory), state reset below.
    const float* pw = xr + (start >= W ? start - W : 0);
    const float* pb = xr + start;
    float*       po = y + (size_t)b * T + start;

    float r = 0.5f;         // h = 1 - 2r = 0

    G8 w, A;
    ldgrp(w, pw);           //  8 outstanding
    ldgrp(A, pb);           // 16 outstanding

    WAITV(8);               // drains w only; A still pending
    chainG<false>(r, w, nullptr);   // w dead after this

    ldgrp(w, pb + G);       // reuse w's registers; outstanding: A(8)+w(8)
    WAITV(8);               // drains A only; w pending

    if (c == 0) r = 0.5f;   // exact h0 = 0 for the first chunk

    chainG<true>(r, A, po); // issues 8 stores -> outstanding [w(8), st(8)]
    WAITV(8);               // drains w (oldest 8); stores remain in flight
    chainG<true>(r, w, po + G);     // final stores drain at s_endpgm
}

extern "C" void kernel_launch(void* const* d_in, const int* in_sizes, int n_in,
                              void* d_out, int out_size, void* d_ws, size_t ws_size,
                              hipStream_t stream) {
    const float* x = (const float*)d_in[0];
    float*       y = (float*)d_out;
    const int total_threads = Bn * C;          // 524288
    const int block = 256;
    const int grid = total_threads / block;    // 2048
    ipe_scan_kernel<<<grid, block, 0, stream>>>(x, y);
}